// Round 2
// baseline (229.772 us; speedup 1.0000x reference)
//
#include <hip/hip_runtime.h>
#include <math.h>

#define SQRT3F     1.7320508075688772f
#define SCALE_T    0.17677669529663687f    // 1/sqrt(32)
#define SCALE_M1   0.025515518153991442f   // C_SCALAR/sqrt(32)
#define SCALE_M2   0.014731391274719739f   // C_SCALAR*inv_sqrt3/sqrt(32)
#define SCALE_M34  0.036084391824351615f   // C_SCALAR/4  (== C_VECTOR*inv_sqrt3/sqrt(16))

// ---------------------------------------------------------------------------
// Precompute: T = emb @ W_s2n * 1/sqrt(32)  (100x32)
//             Ms[l] (48x32) = [W1@Ws * sM1 ; W4@Ws * sM2]
//             Mv[l] (48x16) = [W2@Wv * sM34 ; W3@Wv * sM34]
// ---------------------------------------------------------------------------
__global__ void precompute_kernel(const float* __restrict__ emb,
                                  const float* __restrict__ W_s2n,
                                  const float* __restrict__ W1,
                                  const float* __restrict__ W2,
                                  const float* __restrict__ W3,
                                  const float* __restrict__ W4,
                                  const float* __restrict__ Ws,
                                  const float* __restrict__ Wv,
                                  float* __restrict__ T,
                                  float* __restrict__ Ms,
                                  float* __restrict__ Mv)
{
    const int total = 100*32 + 3*48*32 + 3*48*16;
    for (int idx = blockIdx.x * blockDim.x + threadIdx.x; idx < total;
         idx += gridDim.x * blockDim.x) {
        if (idx < 3200) {
            int r = idx >> 5, c = idx & 31;
            float acc = 0.f;
            for (int k = 0; k < 32; ++k) acc += emb[r*32 + k] * W_s2n[k*32 + c];
            T[idx] = acc * SCALE_T;
        } else if (idx < 3200 + 3*1536) {
            int tix = idx - 3200;
            int l = tix / 1536, rem = tix % 1536;
            int u = rem >> 5, w = rem & 31;
            float acc = 0.f;
            if (u < 32) {
                for (int k = 0; k < 32; ++k)
                    acc += W1[l*1024 + u*32 + k] * Ws[l*1024 + k*32 + w];
                acc *= SCALE_M1;
            } else {
                int uu = u - 32;
                for (int k = 0; k < 32; ++k)
                    acc += W4[l*512 + uu*32 + k] * Ws[l*1024 + k*32 + w];
                acc *= SCALE_M2;
            }
            Ms[l*1536 + u*32 + w] = acc;
        } else {
            int tix = idx - 3200 - 3*1536;
            int l = tix / 768, rem = tix % 768;
            int u = rem >> 4, w = rem & 15;
            float acc = 0.f;
            if (u < 32) {
                for (int k = 0; k < 16; ++k)
                    acc += W2[l*512 + u*16 + k] * Wv[l*256 + k*16 + w];
            } else {
                int uu = u - 32;
                for (int k = 0; k < 16; ++k)
                    acc += W3[l*256 + uu*16 + k] * Wv[l*256 + k*16 + w];
            }
            Mv[l*768 + u*16 + w] = acc * SCALE_M34;
        }
    }
}

// ---------------------------------------------------------------------------
// rowptr[n] = lower_bound(src, n): edges sorted by src (np.nonzero C-order).
// ---------------------------------------------------------------------------
__global__ void rowptr_kernel(const int* __restrict__ src, int E, int N,
                              int* __restrict__ rowptr)
{
    int n = blockIdx.x * blockDim.x + threadIdx.x;
    if (n > N) return;
    int lo = 0, hi = E;
    while (lo < hi) {
        int mid = (lo + hi) >> 1;
        if (src[mid] < n) lo = mid + 1; else hi = mid;
    }
    rowptr[n] = lo;
}

// ---------------------------------------------------------------------------
// sh table: one float4 per edge (sqrt3 * normalized(pos[src]-pos[col]), 0).
// Layer-invariant -> computed once, reused 3x.
// ---------------------------------------------------------------------------
__global__ void sh_kernel(const float* __restrict__ pos,
                          const int* __restrict__ src, const int* __restrict__ col,
                          float4* __restrict__ sh, int E)
{
    int e = blockIdx.x * blockDim.x + threadIdx.x;
    if (e >= E) return;
    int a = src[e], b = col[e];
    float dx = pos[3*a+0] - pos[3*b+0];
    float dy = pos[3*a+1] - pos[3*b+1];
    float dz = pos[3*a+2] - pos[3*b+2];
    float rinv = rsqrtf(dx*dx + dy*dy + dz*dz) * SQRT3F;
    sh[e] = make_float4(dx*rinv, dy*rinv, dz*rinv, 0.f);
}

// ---------------------------------------------------------------------------
// Message-passing layer. Phase 1: 4 lanes/node gather aggregates over the
// node's edge block; write to LDS transposed AT[192][65]. Phase 2: 4 waves
// with wave-uniform output chunks; A from conflict-free ds_read_b32, M from
// scalar (s_load) path. FIRST=true: v_in==0, s_in = T[z].
// ---------------------------------------------------------------------------
template<bool FIRST>
__launch_bounds__(256, 3)
__global__ void layer_kernel(const float* __restrict__ s_in, const float* __restrict__ v_in,
                             const float* __restrict__ T, const int* __restrict__ z,
                             float* __restrict__ s_out, float* __restrict__ v_out,
                             const int* __restrict__ rowptr, const int* __restrict__ colv,
                             const float4* __restrict__ shtab,
                             const float* __restrict__ Ms, const float* __restrict__ Mv,
                             int N)
{
    __shared__ float AT[192*65];

    const int nl = threadIdx.x >> 2;   // node within tile: 0..63
    const int t  = threadIdx.x & 3;
    const int node = blockIdx.x * 64 + nl;

    float a0[8]    = {0.f,0.f,0.f,0.f,0.f,0.f,0.f,0.f};
    float a1[8][3] = {};
    float a2[4][3] = {};
    float a3[4]    = {0.f,0.f,0.f,0.f};

    if (node < N) {
        const int e0 = rowptr[node], e1 = rowptr[node+1];
        for (int e = e0; e < e1; ++e) {
            const int j = colv[e];
            const float4 sh = shtab[e];

            const float4* sp;
            if (FIRST) sp = (const float4*)(T + (size_t)z[j]*32 + 8*t);
            else       sp = (const float4*)(s_in + (size_t)j*32 + 8*t);
            float4 sA = sp[0], sB = sp[1];
            float ss[8] = {sA.x,sA.y,sA.z,sA.w,sB.x,sB.y,sB.z,sB.w};
            #pragma unroll
            for (int k = 0; k < 8; ++k) {
                a0[k] += ss[k];
                a1[k][0] = fmaf(ss[k], sh.x, a1[k][0]);
                a1[k][1] = fmaf(ss[k], sh.y, a1[k][1]);
                a1[k][2] = fmaf(ss[k], sh.z, a1[k][2]);
            }
            if (!FIRST) {
                const float4* vp = (const float4*)(v_in + (size_t)j*48 + 12*t);
                float4 vA = vp[0], vB = vp[1], vC = vp[2];
                float vv[4][3] = {{vA.x,vA.y,vA.z},{vA.w,vB.x,vB.y},
                                  {vB.z,vB.w,vC.x},{vC.y,vC.z,vC.w}};
                #pragma unroll
                for (int k = 0; k < 4; ++k) {
                    a2[k][0] += vv[k][0]; a2[k][1] += vv[k][1]; a2[k][2] += vv[k][2];
                    a3[k] = fmaf(vv[k][0], sh.x,
                            fmaf(vv[k][1], sh.y, fmaf(vv[k][2], sh.z, a3[k])));
                }
            }
        }
    }

    // stage aggregates -> LDS (transposed; 65-stride => worst 2-way = free)
    #pragma unroll
    for (int k = 0; k < 8; ++k) AT[(8*t + k)*65 + nl] = a0[k];
    #pragma unroll
    for (int k = 0; k < 8; ++k) {
        #pragma unroll
        for (int i = 0; i < 3; ++i)
            AT[(48 + 3*(8*t + k) + i)*65 + nl] = a1[k][i];
    }
    if (!FIRST) {
        #pragma unroll
        for (int k = 0; k < 4; ++k) AT[(32 + 4*t + k)*65 + nl] = a3[k];
        #pragma unroll
        for (int k = 0; k < 4; ++k) {
            #pragma unroll
            for (int i = 0; i < 3; ++i)
                AT[(144 + 3*(4*t + k) + i)*65 + nl] = a2[k][i];
        }
    }
    __syncthreads();

    const int NU = FIRST ? 32 : 48;
    const int wq = threadIdx.x >> 6;
    const int ln = threadIdx.x & 63;
    const int n2 = blockIdx.x * 64 + ln;

    if (wq < 2) {
        // scalar outputs wb..wb+15
        const int wb = __builtin_amdgcn_readfirstlane(wq * 16);
        float acc[16] = {};
        #pragma unroll 2
        for (int u = 0; u < NU; ++u) {
            float a = AT[u*65 + ln];
            const float* m = Ms + u*32 + wb;
            #pragma unroll
            for (int w = 0; w < 16; ++w) acc[w] = fmaf(a, m[w], acc[w]);
        }
        if (n2 < N) {
            const float4* sip;
            if (FIRST) sip = (const float4*)(T + (size_t)z[n2]*32 + wb);
            else       sip = (const float4*)(s_in + (size_t)n2*32 + wb);
            float4* sop = (float4*)(s_out + (size_t)n2*32 + wb);
            #pragma unroll
            for (int q = 0; q < 4; ++q) {
                float4 b = sip[q];
                float4 o;
                o.x = b.x + fmaxf(acc[q*4+0], 0.f);
                o.y = b.y + fmaxf(acc[q*4+1], 0.f);
                o.z = b.z + fmaxf(acc[q*4+2], 0.f);
                o.w = b.w + fmaxf(acc[q*4+3], 0.f);
                sop[q] = o;
            }
        }
    } else {
        // vector outputs channels wb..wb+7 (24 floats)
        const int wb = __builtin_amdgcn_readfirstlane((wq - 2) * 8);
        float acc[24] = {};
        #pragma unroll 2
        for (int u = 0; u < NU; ++u) {
            float ax = AT[(48 + 3*u + 0)*65 + ln];
            float ay = AT[(48 + 3*u + 1)*65 + ln];
            float az = AT[(48 + 3*u + 2)*65 + ln];
            const float* m = Mv + u*16 + wb;
            #pragma unroll
            for (int w = 0; w < 8; ++w) {
                float mw = m[w];
                acc[w*3+0] = fmaf(mw, ax, acc[w*3+0]);
                acc[w*3+1] = fmaf(mw, ay, acc[w*3+1]);
                acc[w*3+2] = fmaf(mw, az, acc[w*3+2]);
            }
        }
        if (n2 < N) {
            float4* vop = (float4*)(v_out + (size_t)n2*48 + wb*3);
            if (FIRST) {
                #pragma unroll
                for (int q = 0; q < 6; ++q) {
                    float4 o;
                    o.x = fmaxf(acc[q*4+0], 0.f);
                    o.y = fmaxf(acc[q*4+1], 0.f);
                    o.z = fmaxf(acc[q*4+2], 0.f);
                    o.w = fmaxf(acc[q*4+3], 0.f);
                    vop[q] = o;
                }
            } else {
                const float4* vip = (const float4*)(v_in + (size_t)n2*48 + wb*3);
                #pragma unroll
                for (int q = 0; q < 6; ++q) {
                    float4 b = vip[q];
                    float4 o;
                    o.x = b.x + fmaxf(acc[q*4+0], 0.f);
                    o.y = b.y + fmaxf(acc[q*4+1], 0.f);
                    o.z = b.z + fmaxf(acc[q*4+2], 0.f);
                    o.w = b.w + fmaxf(acc[q*4+3], 0.f);
                    vop[q] = o;
                }
            }
        }
    }
}

// ---------------------------------------------------------------------------
// Pool (float4): hg viewed as [B][20] float4s; f4<8 -> s, else v.
// ---------------------------------------------------------------------------
__global__ void pool_kernel(const float* __restrict__ s, const float* __restrict__ v,
                            float4* __restrict__ hg, int B)
{
    int idx = blockIdx.x * blockDim.x + threadIdx.x;
    if (idx >= B*20) return;
    int g = idx / 20, f4 = idx - g*20;
    int base = g * 32;
    float4 acc = make_float4(0.f, 0.f, 0.f, 0.f);
    if (f4 < 8) {
        const float4* sp = (const float4*)(s) + f4;
        for (int k = 0; k < 32; ++k) {
            float4 x = sp[(size_t)(base+k)*8];
            acc.x += x.x; acc.y += x.y; acc.z += x.z; acc.w += x.w;
        }
    } else {
        const float4* vp = (const float4*)(v) + (f4 - 8);
        for (int k = 0; k < 32; ++k) {
            float4 x = vp[(size_t)(base+k)*12];
            acc.x += x.x; acc.y += x.y; acc.z += x.z; acc.w += x.w;
        }
    }
    hg[idx] = acc;
}

// ---------------------------------------------------------------------------
// MLP head: 4 graphs per block. Stage1: hg via s_load, Wr1 shared across 4
// graphs. Stage2: split-K (2 halves), h1 broadcast float4 reads from LDS.
// ---------------------------------------------------------------------------
__launch_bounds__(256)
__global__ void mlp_kernel(const float* __restrict__ hg,
                           const float* __restrict__ Wr1, const float* __restrict__ br1,
                           const float* __restrict__ Wr2, const float* __restrict__ br2,
                           float* __restrict__ out, int B)
{
    __shared__ __align__(16) float h1[4][256];
    __shared__ float red[4][128];
    const int g0 = blockIdx.x * 4;
    const int w = threadIdx.x;

    float acc0 = br1[w];
    float acc1 = acc0, acc2 = acc0, acc3 = acc0;
    #pragma unroll 4
    for (int f = 0; f < 80; ++f) {
        float wv = Wr1[f*256 + w];
        acc0 = fmaf(hg[(size_t)(g0+0)*80 + f], wv, acc0);
        acc1 = fmaf(hg[(size_t)(g0+1)*80 + f], wv, acc1);
        acc2 = fmaf(hg[(size_t)(g0+2)*80 + f], wv, acc2);
        acc3 = fmaf(hg[(size_t)(g0+3)*80 + f], wv, acc3);
    }
    h1[0][w] = fmaxf(acc0, 0.f);
    h1[1][w] = fmaxf(acc1, 0.f);
    h1[2][w] = fmaxf(acc2, 0.f);
    h1[3][w] = fmaxf(acc3, 0.f);
    __syncthreads();

    const int w2 = threadIdx.x & 127, kh = threadIdx.x >> 7;
    const float4* h1v = (const float4*)(&h1[0][0]);   // [4][64] float4 view
    float s0 = 0.f, s1 = 0.f, s2 = 0.f, s3 = 0.f;
    #pragma unroll 2
    for (int k4 = kh*32; k4 < kh*32 + 32; ++k4) {
        float4 hA = h1v[0*64 + k4];
        float4 hB = h1v[1*64 + k4];
        float4 hC = h1v[2*64 + k4];
        float4 hD = h1v[3*64 + k4];
        int k = k4 * 4;
        float m0 = Wr2[(size_t)(k+0)*128 + w2];
        float m1 = Wr2[(size_t)(k+1)*128 + w2];
        float m2 = Wr2[(size_t)(k+2)*128 + w2];
        float m3 = Wr2[(size_t)(k+3)*128 + w2];
        s0 = fmaf(hA.x,m0, fmaf(hA.y,m1, fmaf(hA.z,m2, fmaf(hA.w,m3, s0))));
        s1 = fmaf(hB.x,m0, fmaf(hB.y,m1, fmaf(hB.z,m2, fmaf(hB.w,m3, s1))));
        s2 = fmaf(hC.x,m0, fmaf(hC.y,m1, fmaf(hC.z,m2, fmaf(hC.w,m3, s2))));
        s3 = fmaf(hD.x,m0, fmaf(hD.y,m1, fmaf(hD.z,m2, fmaf(hD.w,m3, s3))));
    }
    if (kh) {
        red[0][w2] = s0; red[1][w2] = s1; red[2][w2] = s2; red[3][w2] = s3;
    }
    __syncthreads();
    if (!kh) {
        float b = br2[w2];
        out[(size_t)(g0+0)*128 + w2] = s0 + red[0][w2] + b;
        out[(size_t)(g0+1)*128 + w2] = s1 + red[1][w2] + b;
        out[(size_t)(g0+2)*128 + w2] = s2 + red[2][w2] + b;
        out[(size_t)(g0+3)*128 + w2] = s3 + red[3][w2] + b;
    }
}

// ---------------------------------------------------------------------------
extern "C" void kernel_launch(void* const* d_in, const int* in_sizes, int n_in,
                              void* d_out, int out_size, void* d_ws, size_t ws_size,
                              hipStream_t stream)
{
    const float* pos   = (const float*)d_in[0];
    const int*   z     = (const int*)d_in[1];
    const int*   eidx  = (const int*)d_in[3];
    const float* emb   = (const float*)d_in[5];
    const float* W_s2n = (const float*)d_in[6];
    const float* W1    = (const float*)d_in[7];
    const float* W2    = (const float*)d_in[8];
    const float* W3    = (const float*)d_in[9];
    const float* W4    = (const float*)d_in[10];
    const float* Ws    = (const float*)d_in[11];
    const float* Wv    = (const float*)d_in[12];
    const float* Wr1   = (const float*)d_in[13];
    const float* br1   = (const float*)d_in[14];
    const float* Wr2   = (const float*)d_in[15];
    const float* br2   = (const float*)d_in[16];
    float* out = (float*)d_out;

    const int N = in_sizes[0] / 3;
    const int E = in_sizes[3] / 2;
    const int B = out_size / 128;

    const int* src = eidx;
    const int* col = eidx + E;

    // workspace layout (16B-aligned chunks)
    char* p = (char*)d_ws;
    float4* sh = (float4*)p;  p += (size_t)E * 16;
    float* T  = (float*)p;    p += 3200 * 4;
    float* Ms = (float*)p;    p += 3 * 1536 * 4;
    float* Mv = (float*)p;    p += 3 * 768 * 4;
    int* rowptr = (int*)p;    p += (((size_t)(N + 1) * 4 + 15) & ~(size_t)15);
    float* s0 = (float*)p;    p += (size_t)N * 32 * 4;
    float* s1 = (float*)p;    p += (size_t)N * 32 * 4;
    float* v0 = (float*)p;    p += (size_t)N * 48 * 4;
    float* v1 = (float*)p;    p += (size_t)N * 48 * 4;
    float* hg = (float*)p;    p += (size_t)B * 80 * 4;

    precompute_kernel<<<40, 256, 0, stream>>>(emb, W_s2n, W1, W2, W3, W4, Ws, Wv,
                                              T, Ms, Mv);
    rowptr_kernel<<<(N + 1 + 255) / 256, 256, 0, stream>>>(src, E, N, rowptr);
    sh_kernel<<<(E + 255) / 256, 256, 0, stream>>>(pos, src, col, sh, E);

    const int nblk = (N + 63) / 64;
    // layer 1: inputs are T[z] (scalars) and zero vectors -> writes s1, v1
    layer_kernel<true><<<nblk, 256, 0, stream>>>(nullptr, nullptr, T, z,
                                                 s1, v1, rowptr, col, sh,
                                                 Ms + 0*1536, Mv + 0*768, N);
    // layer 2: s1,v1 -> s0,v0
    layer_kernel<false><<<nblk, 256, 0, stream>>>(s1, v1, T, z,
                                                  s0, v0, rowptr, col, sh,
                                                  Ms + 1*1536, Mv + 1*768, N);
    // layer 3: s0,v0 -> s1,v1
    layer_kernel<false><<<nblk, 256, 0, stream>>>(s0, v0, T, z,
                                                  s1, v1, rowptr, col, sh,
                                                  Ms + 2*1536, Mv + 2*768, N);

    pool_kernel<<<((size_t)B * 20 + 255) / 256, 256, 0, stream>>>(s1, v1, (float4*)hg, B);
    mlp_kernel<<<B / 4, 256, 0, stream>>>(hg, Wr1, br1, Wr2, br2, out, B);
}

// Round 3
// 203.318 us; speedup vs baseline: 1.1301x; 1.1301x over previous
//
#include <hip/hip_runtime.h>
#include <math.h>

#define SQRT3F     1.7320508075688772f
#define SCALE_T    0.17677669529663687f    // 1/sqrt(32)
#define SCALE_M1   0.025515518153991442f   // C_SCALAR/sqrt(32)
#define SCALE_M2   0.014731391274719739f   // C_SCALAR*inv_sqrt3/sqrt(32)
#define SCALE_M34  0.036084391824351615f   // C_SCALAR/4  (== C_VECTOR*inv_sqrt3/sqrt(16))

#define SSTR 36    // LDS stride (floats) for s rows: 144 B, 16B-aligned, 8 bank offsets
#define VSTR 52    // LDS stride (floats) for v rows: 208 B, 16B-aligned

// quad broadcast of lane TT via DPP (VALU pipe, not DS)
template<int TT>
__device__ __forceinline__ float qb(float x) {
    return __int_as_float(__builtin_amdgcn_update_dpp(
        0, __float_as_int(x), TT * 0x55, 0xF, 0xF, true));
}

// ---------------------------------------------------------------------------
// Prep kernel: one dispatch does (a) jsh table: float4(sh_xyz, bits(j&63)) per
// edge, (b) rowptr via binary search, (c) folded weight matrices T/Ms/Mv.
// ---------------------------------------------------------------------------
__global__ void prep_kernel(const float* __restrict__ pos,
                            const int* __restrict__ src, const int* __restrict__ col,
                            int E, int N,
                            const float* __restrict__ emb,
                            const float* __restrict__ W_s2n,
                            const float* __restrict__ W1, const float* __restrict__ W2,
                            const float* __restrict__ W3, const float* __restrict__ W4,
                            const float* __restrict__ Ws, const float* __restrict__ Wv,
                            float4* __restrict__ jsh, int* __restrict__ rowptr,
                            float* __restrict__ T, float* __restrict__ Ms,
                            float* __restrict__ Mv)
{
    int idx = blockIdx.x * blockDim.x + threadIdx.x;
    if (idx < E) {
        int e = idx;
        int n = src[e], j = col[e];
        float dx = pos[3*n+0] - pos[3*j+0];
        float dy = pos[3*n+1] - pos[3*j+1];
        float dz = pos[3*n+2] - pos[3*j+2];
        float rinv = rsqrtf(dx*dx + dy*dy + dz*dz) * SQRT3F;
        jsh[e] = make_float4(dx*rinv, dy*rinv, dz*rinv, __int_as_float(j & 63));
        return;
    }
    idx -= E;
    if (idx <= N) {
        int lo = 0, hi = E;
        while (lo < hi) {
            int mid = (lo + hi) >> 1;
            if (src[mid] < idx) lo = mid + 1; else hi = mid;
        }
        rowptr[idx] = lo;
        return;
    }
    idx -= (N + 1);
    if (idx < 3200) {
        int r = idx >> 5, c = idx & 31;
        float acc = 0.f;
        for (int k = 0; k < 32; ++k) acc += emb[r*32 + k] * W_s2n[k*32 + c];
        T[idx] = acc * SCALE_T;
    } else if (idx < 3200 + 3*1536) {
        int tix = idx - 3200;
        int l = tix / 1536, rem = tix % 1536;
        int u = rem >> 5, w = rem & 31;
        float acc = 0.f;
        if (u < 32) {
            for (int k = 0; k < 32; ++k)
                acc += W1[l*1024 + u*32 + k] * Ws[l*1024 + k*32 + w];
            acc *= SCALE_M1;
        } else {
            int uu = u - 32;
            for (int k = 0; k < 32; ++k)
                acc += W4[l*512 + uu*32 + k] * Ws[l*1024 + k*32 + w];
            acc *= SCALE_M2;
        }
        Ms[l*1536 + u*32 + w] = acc;
    } else if (idx < 3200 + 3*1536 + 3*768) {
        int tix = idx - 3200 - 3*1536;
        int l = tix / 768, rem = tix % 768;
        int u = rem >> 4, w = rem & 15;
        float acc = 0.f;
        if (u < 32) {
            for (int k = 0; k < 16; ++k)
                acc += W2[l*512 + u*16 + k] * Wv[l*256 + k*16 + w];
        } else {
            int uu = u - 32;
            for (int k = 0; k < 16; ++k)
                acc += W3[l*256 + uu*16 + k] * Wv[l*256 + k*16 + w];
        }
        Mv[l*768 + u*16 + w] = acc * SCALE_M34;
    }
}

// ---------------------------------------------------------------------------
// Phase-2 contribution from quad-lane TT: broadcast its aggregates (DPP) and
// FMA against M rows u = 8*TT+k (and 32+4*TT+k when hasv).
// ---------------------------------------------------------------------------
template<int TT>
__device__ __forceinline__ void p2(const float (&a0)[8], const float (&a1)[8][3],
                                   const float (&a2)[4][3], const float (&a3)[4],
                                   const float* __restrict__ Msg,
                                   const float* __restrict__ Mvg,
                                   int t, bool hasv,
                                   float (&po)[8], float (&pv)[12])
{
    #pragma unroll
    for (int k = 0; k < 8; ++k) {
        const int u = 8*TT + k;
        float a  = qb<TT>(a0[k]);
        float bx = qb<TT>(a1[k][0]);
        float by = qb<TT>(a1[k][1]);
        float bz = qb<TT>(a1[k][2]);
        const float4* r = (const float4*)(Msg + u*32 + 8*t);
        float4 rA = r[0], rB = r[1];
        po[0]=fmaf(a,rA.x,po[0]); po[1]=fmaf(a,rA.y,po[1]);
        po[2]=fmaf(a,rA.z,po[2]); po[3]=fmaf(a,rA.w,po[3]);
        po[4]=fmaf(a,rB.x,po[4]); po[5]=fmaf(a,rB.y,po[5]);
        po[6]=fmaf(a,rB.z,po[6]); po[7]=fmaf(a,rB.w,po[7]);
        float4 m = *(const float4*)(Mvg + u*16 + 4*t);
        pv[0]=fmaf(m.x,bx,pv[0]);  pv[1]=fmaf(m.x,by,pv[1]);  pv[2]=fmaf(m.x,bz,pv[2]);
        pv[3]=fmaf(m.y,bx,pv[3]);  pv[4]=fmaf(m.y,by,pv[4]);  pv[5]=fmaf(m.y,bz,pv[5]);
        pv[6]=fmaf(m.z,bx,pv[6]);  pv[7]=fmaf(m.z,by,pv[7]);  pv[8]=fmaf(m.z,bz,pv[8]);
        pv[9]=fmaf(m.w,bx,pv[9]);  pv[10]=fmaf(m.w,by,pv[10]); pv[11]=fmaf(m.w,bz,pv[11]);
    }
    if (hasv) {
        #pragma unroll
        for (int k = 0; k < 4; ++k) {
            const int u = 32 + 4*TT + k;
            float a  = qb<TT>(a3[k]);
            float bx = qb<TT>(a2[k][0]);
            float by = qb<TT>(a2[k][1]);
            float bz = qb<TT>(a2[k][2]);
            const float4* r = (const float4*)(Msg + u*32 + 8*t);
            float4 rA = r[0], rB = r[1];
            po[0]=fmaf(a,rA.x,po[0]); po[1]=fmaf(a,rA.y,po[1]);
            po[2]=fmaf(a,rA.z,po[2]); po[3]=fmaf(a,rA.w,po[3]);
            po[4]=fmaf(a,rB.x,po[4]); po[5]=fmaf(a,rB.y,po[5]);
            po[6]=fmaf(a,rB.z,po[6]); po[7]=fmaf(a,rB.w,po[7]);
            float4 m = *(const float4*)(Mvg + u*16 + 4*t);
            pv[0]=fmaf(m.x,bx,pv[0]);  pv[1]=fmaf(m.x,by,pv[1]);  pv[2]=fmaf(m.x,bz,pv[2]);
            pv[3]=fmaf(m.y,bx,pv[3]);  pv[4]=fmaf(m.y,by,pv[4]);  pv[5]=fmaf(m.y,bz,pv[5]);
            pv[6]=fmaf(m.z,bx,pv[6]);  pv[7]=fmaf(m.z,by,pv[7]);  pv[8]=fmaf(m.z,bz,pv[8]);
            pv[9]=fmaf(m.w,bx,pv[9]);  pv[10]=fmaf(m.w,by,pv[10]); pv[11]=fmaf(m.w,bz,pv[11]);
        }
    }
}

// ---------------------------------------------------------------------------
// Fused GNN: one block = 2 graphs (64 nodes, 256 threads, 4 lanes/node).
// s,v live in LDS across all 3 layers; gather is ds_read_b128; pool fused.
// ---------------------------------------------------------------------------
__global__ __launch_bounds__(256, 4)
void gnn_kernel(const float* __restrict__ T, const int* __restrict__ z,
                const int* __restrict__ rowptr, const float4* __restrict__ jsh,
                const float* __restrict__ Ms, const float* __restrict__ Mv,
                float* __restrict__ hg, int N)
{
    __shared__ __align__(16) float sS[64*SSTR];
    __shared__ __align__(16) float sV[64*VSTR];
    __shared__ int rp[65];

    const int base = blockIdx.x * 64;
    const int tid = threadIdx.x;

    if (tid < 65) rp[tid] = rowptr[base + tid];
    for (int i = tid; i < 64*VSTR; i += 256) sV[i] = 0.f;
    for (int i = tid; i < 2048; i += 256) {
        int n = i >> 5, c = i & 31;
        sS[n*SSTR + c] = T[z[base + n]*32 + c];
    }
    __syncthreads();

    const int nl = tid >> 2;    // node 0..63 within block
    const int t  = tid & 3;     // quad lane: s-channels 8t.., v-channels 4t..
    const int e0 = rp[nl], e1 = rp[nl + 1];

    for (int lay = 0; lay < 3; ++lay) {
        const bool hasv = (lay != 0);
        const float* Msg = Ms + lay*1536;
        const float* Mvg = Mv + lay*768;

        float a0[8]    = {};
        float a1[8][3] = {};
        float a2[4][3] = {};
        float a3[4]    = {};

        if (!hasv) {
            for (int e = e0; e < e1; ++e) {
                float4 js = jsh[e];
                int jl = __float_as_int(js.w);
                const float* Sj = sS + jl*SSTR + 8*t;
                float4 sA = *(const float4*)Sj;
                float4 sB = *(const float4*)(Sj + 4);
                float ssv[8] = {sA.x,sA.y,sA.z,sA.w,sB.x,sB.y,sB.z,sB.w};
                #pragma unroll
                for (int k = 0; k < 8; ++k) {
                    a0[k] += ssv[k];
                    a1[k][0] = fmaf(ssv[k], js.x, a1[k][0]);
                    a1[k][1] = fmaf(ssv[k], js.y, a1[k][1]);
                    a1[k][2] = fmaf(ssv[k], js.z, a1[k][2]);
                }
            }
        } else {
            for (int e = e0; e < e1; ++e) {
                float4 js = jsh[e];
                int jl = __float_as_int(js.w);
                const float* Sj = sS + jl*SSTR + 8*t;
                const float* Vj = sV + jl*VSTR + 12*t;
                float4 sA = *(const float4*)Sj;
                float4 sB = *(const float4*)(Sj + 4);
                float4 vA = *(const float4*)Vj;
                float4 vB = *(const float4*)(Vj + 4);
                float4 vC = *(const float4*)(Vj + 8);
                float ssv[8] = {sA.x,sA.y,sA.z,sA.w,sB.x,sB.y,sB.z,sB.w};
                #pragma unroll
                for (int k = 0; k < 8; ++k) {
                    a0[k] += ssv[k];
                    a1[k][0] = fmaf(ssv[k], js.x, a1[k][0]);
                    a1[k][1] = fmaf(ssv[k], js.y, a1[k][1]);
                    a1[k][2] = fmaf(ssv[k], js.z, a1[k][2]);
                }
                float vv[4][3] = {{vA.x,vA.y,vA.z},{vA.w,vB.x,vB.y},
                                  {vB.z,vB.w,vC.x},{vC.y,vC.z,vC.w}};
                #pragma unroll
                for (int k = 0; k < 4; ++k) {
                    a2[k][0] += vv[k][0]; a2[k][1] += vv[k][1]; a2[k][2] += vv[k][2];
                    a3[k] = fmaf(vv[k][0], js.x,
                            fmaf(vv[k][1], js.y, fmaf(vv[k][2], js.z, a3[k])));
                }
            }
        }
        __syncthreads();   // all gathers done before in-place update

        float po[8]  = {};
        float pv[12] = {};
        p2<0>(a0, a1, a2, a3, Msg, Mvg, t, hasv, po, pv);
        p2<1>(a0, a1, a2, a3, Msg, Mvg, t, hasv, po, pv);
        p2<2>(a0, a1, a2, a3, Msg, Mvg, t, hasv, po, pv);
        p2<3>(a0, a1, a2, a3, Msg, Mvg, t, hasv, po, pv);

        // residual + relu, in-place (lane-owned slices only)
        float* Sp = sS + nl*SSTR + 8*t;
        float4 s0 = *(float4*)Sp, s1 = *(float4*)(Sp + 4);
        s0.x += fmaxf(po[0],0.f); s0.y += fmaxf(po[1],0.f);
        s0.z += fmaxf(po[2],0.f); s0.w += fmaxf(po[3],0.f);
        s1.x += fmaxf(po[4],0.f); s1.y += fmaxf(po[5],0.f);
        s1.z += fmaxf(po[6],0.f); s1.w += fmaxf(po[7],0.f);
        *(float4*)Sp = s0; *(float4*)(Sp + 4) = s1;

        float* Vp = sV + nl*VSTR + 12*t;
        float4 v0 = *(float4*)Vp, v1 = *(float4*)(Vp + 4), v2 = *(float4*)(Vp + 8);
        v0.x += fmaxf(pv[0],0.f);  v0.y += fmaxf(pv[1],0.f);
        v0.z += fmaxf(pv[2],0.f);  v0.w += fmaxf(pv[3],0.f);
        v1.x += fmaxf(pv[4],0.f);  v1.y += fmaxf(pv[5],0.f);
        v1.z += fmaxf(pv[6],0.f);  v1.w += fmaxf(pv[7],0.f);
        v2.x += fmaxf(pv[8],0.f);  v2.y += fmaxf(pv[9],0.f);
        v2.z += fmaxf(pv[10],0.f); v2.w += fmaxf(pv[11],0.f);
        *(float4*)Vp = v0; *(float4*)(Vp + 4) = v1; *(float4*)(Vp + 8) = v2;

        __syncthreads();
    }

    // fused sum-pool: 2 graphs x 80 features
    if (tid < 160) {
        int g = tid / 80, f = tid - g*80;
        float acc = 0.f;
        if (f < 32) {
            for (int k = 0; k < 32; ++k) acc += sS[(g*32 + k)*SSTR + f];
        } else {
            int c = f - 32;
            for (int k = 0; k < 32; ++k) acc += sV[(g*32 + k)*VSTR + c];
        }
        hg[(size_t)(blockIdx.x*2 + g)*80 + f] = acc;
    }
}

// ---------------------------------------------------------------------------
// MLP head: 4 graphs per block; hg via scalar loads, Wr1/Wr2 shared; split-K.
// ---------------------------------------------------------------------------
__launch_bounds__(256)
__global__ void mlp_kernel(const float* __restrict__ hg,
                           const float* __restrict__ Wr1, const float* __restrict__ br1,
                           const float* __restrict__ Wr2, const float* __restrict__ br2,
                           float* __restrict__ out, int B)
{
    __shared__ __align__(16) float h1[4][256];
    __shared__ float red[4][128];
    const int g0 = blockIdx.x * 4;
    const int w = threadIdx.x;

    float acc0 = br1[w];
    float acc1 = acc0, acc2 = acc0, acc3 = acc0;
    #pragma unroll 4
    for (int f = 0; f < 80; ++f) {
        float wv = Wr1[f*256 + w];
        acc0 = fmaf(hg[(size_t)(g0+0)*80 + f], wv, acc0);
        acc1 = fmaf(hg[(size_t)(g0+1)*80 + f], wv, acc1);
        acc2 = fmaf(hg[(size_t)(g0+2)*80 + f], wv, acc2);
        acc3 = fmaf(hg[(size_t)(g0+3)*80 + f], wv, acc3);
    }
    h1[0][w] = fmaxf(acc0, 0.f);
    h1[1][w] = fmaxf(acc1, 0.f);
    h1[2][w] = fmaxf(acc2, 0.f);
    h1[3][w] = fmaxf(acc3, 0.f);
    __syncthreads();

    const int w2 = threadIdx.x & 127, kh = threadIdx.x >> 7;
    const float4* h1v = (const float4*)(&h1[0][0]);   // [4][64] float4 view
    float s0 = 0.f, s1 = 0.f, s2 = 0.f, s3 = 0.f;
    #pragma unroll 2
    for (int k4 = kh*32; k4 < kh*32 + 32; ++k4) {
        float4 hA = h1v[0*64 + k4];
        float4 hB = h1v[1*64 + k4];
        float4 hC = h1v[2*64 + k4];
        float4 hD = h1v[3*64 + k4];
        int k = k4 * 4;
        float m0 = Wr2[(size_t)(k+0)*128 + w2];
        float m1 = Wr2[(size_t)(k+1)*128 + w2];
        float m2 = Wr2[(size_t)(k+2)*128 + w2];
        float m3 = Wr2[(size_t)(k+3)*128 + w2];
        s0 = fmaf(hA.x,m0, fmaf(hA.y,m1, fmaf(hA.z,m2, fmaf(hA.w,m3, s0))));
        s1 = fmaf(hB.x,m0, fmaf(hB.y,m1, fmaf(hB.z,m2, fmaf(hB.w,m3, s1))));
        s2 = fmaf(hC.x,m0, fmaf(hC.y,m1, fmaf(hC.z,m2, fmaf(hC.w,m3, s2))));
        s3 = fmaf(hD.x,m0, fmaf(hD.y,m1, fmaf(hD.z,m2, fmaf(hD.w,m3, s3))));
    }
    if (kh) {
        red[0][w2] = s0; red[1][w2] = s1; red[2][w2] = s2; red[3][w2] = s3;
    }
    __syncthreads();
    if (!kh) {
        float b = br2[w2];
        out[(size_t)(g0+0)*128 + w2] = s0 + red[0][w2] + b;
        out[(size_t)(g0+1)*128 + w2] = s1 + red[1][w2] + b;
        out[(size_t)(g0+2)*128 + w2] = s2 + red[2][w2] + b;
        out[(size_t)(g0+3)*128 + w2] = s3 + red[3][w2] + b;
    }
}

// ---------------------------------------------------------------------------
extern "C" void kernel_launch(void* const* d_in, const int* in_sizes, int n_in,
                              void* d_out, int out_size, void* d_ws, size_t ws_size,
                              hipStream_t stream)
{
    const float* pos   = (const float*)d_in[0];
    const int*   z     = (const int*)d_in[1];
    const int*   eidx  = (const int*)d_in[3];
    const float* emb   = (const float*)d_in[5];
    const float* W_s2n = (const float*)d_in[6];
    const float* W1    = (const float*)d_in[7];
    const float* W2    = (const float*)d_in[8];
    const float* W3    = (const float*)d_in[9];
    const float* W4    = (const float*)d_in[10];
    const float* Ws    = (const float*)d_in[11];
    const float* Wv    = (const float*)d_in[12];
    const float* Wr1   = (const float*)d_in[13];
    const float* br1   = (const float*)d_in[14];
    const float* Wr2   = (const float*)d_in[15];
    const float* br2   = (const float*)d_in[16];
    float* out = (float*)d_out;

    const int N = in_sizes[0] / 3;
    const int E = in_sizes[3] / 2;
    const int B = out_size / 128;

    const int* src = eidx;
    const int* col = eidx + E;

    // workspace layout (16B-aligned chunks)
    char* p = (char*)d_ws;
    float4* jsh = (float4*)p;  p += (size_t)E * 16;
    float* T  = (float*)p;     p += 3200 * 4;
    float* Ms = (float*)p;     p += 3 * 1536 * 4;
    float* Mv = (float*)p;     p += 3 * 768 * 4;
    int* rowptr = (int*)p;     p += (((size_t)(N + 1) * 4 + 15) & ~(size_t)15);
    float* hg = (float*)p;     p += (size_t)B * 80 * 4;

    const int prep_total = E + (N + 1) + 3200 + 3*1536 + 3*768;
    prep_kernel<<<(prep_total + 255) / 256, 256, 0, stream>>>(
        pos, src, col, E, N, emb, W_s2n, W1, W2, W3, W4, Ws, Wv,
        jsh, rowptr, T, Ms, Mv);

    gnn_kernel<<<(N + 63) / 64, 256, 0, stream>>>(T, z, rowptr, jsh, Ms, Mv, hg, N);

    mlp_kernel<<<B / 4, 256, 0, stream>>>(hg, Wr1, br1, Wr2, br2, out, B);
}

// Round 4
// 192.340 us; speedup vs baseline: 1.1946x; 1.0571x over previous
//
#include <hip/hip_runtime.h>
#include <hip/hip_fp16.h>
#include <math.h>

#define SQRT3F     1.7320508075688772f
#define SCALE_T    0.17677669529663687f    // 1/sqrt(32)
#define SCALE_M1   0.025515518153991442f   // C_SCALAR/sqrt(32)
#define SCALE_M2   0.014731391274719739f   // C_SCALAR*inv_sqrt3/sqrt(32)
#define SCALE_M34  0.036084391824351615f   // C_SCALAR/4  (== C_VECTOR*inv_sqrt3/sqrt(16))

#define SSTR 36    // LDS stride (floats) for s rows
#define VSTR 52    // LDS stride (floats) for v rows
#define ECAP 2048  // max edges per 64-node block: 64*31=1984 < 2048 (within-graph edges only)

// quad broadcast of lane TT via DPP (VALU pipe, not DS)
template<int TT>
__device__ __forceinline__ float qb(float x) {
    return __int_as_float(__builtin_amdgcn_update_dpp(
        0, __float_as_int(x), TT * 0x55, 0xF, 0xF, true));
}

// ---------------------------------------------------------------------------
// Prep kernel: (a) jsh table float4(sh_xyz, bits(j&63)) per edge,
// (b) rowptr via binary search, (c) folded weight matrices T/Ms/Mv.
// ---------------------------------------------------------------------------
__global__ void prep_kernel(const float* __restrict__ pos,
                            const int* __restrict__ src, const int* __restrict__ col,
                            int E, int N,
                            const float* __restrict__ emb,
                            const float* __restrict__ W_s2n,
                            const float* __restrict__ W1, const float* __restrict__ W2,
                            const float* __restrict__ W3, const float* __restrict__ W4,
                            const float* __restrict__ Ws, const float* __restrict__ Wv,
                            float4* __restrict__ jsh, int* __restrict__ rowptr,
                            float* __restrict__ T, float* __restrict__ Ms,
                            float* __restrict__ Mv)
{
    int idx = blockIdx.x * blockDim.x + threadIdx.x;
    if (idx < E) {
        int e = idx;
        int n = src[e], j = col[e];
        float dx = pos[3*n+0] - pos[3*j+0];
        float dy = pos[3*n+1] - pos[3*j+1];
        float dz = pos[3*n+2] - pos[3*j+2];
        float rinv = rsqrtf(dx*dx + dy*dy + dz*dz) * SQRT3F;
        jsh[e] = make_float4(dx*rinv, dy*rinv, dz*rinv, __int_as_float(j & 63));
        return;
    }
    idx -= E;
    if (idx <= N) {
        int lo = 0, hi = E;
        while (lo < hi) {
            int mid = (lo + hi) >> 1;
            if (src[mid] < idx) lo = mid + 1; else hi = mid;
        }
        rowptr[idx] = lo;
        return;
    }
    idx -= (N + 1);
    if (idx < 3200) {
        int r = idx >> 5, c = idx & 31;
        float acc = 0.f;
        for (int k = 0; k < 32; ++k) acc += emb[r*32 + k] * W_s2n[k*32 + c];
        T[idx] = acc * SCALE_T;
    } else if (idx < 3200 + 3*1536) {
        int tix = idx - 3200;
        int l = tix / 1536, rem = tix % 1536;
        int u = rem >> 5, w = rem & 31;
        float acc = 0.f;
        if (u < 32) {
            for (int k = 0; k < 32; ++k)
                acc += W1[l*1024 + u*32 + k] * Ws[l*1024 + k*32 + w];
            acc *= SCALE_M1;
        } else {
            int uu = u - 32;
            for (int k = 0; k < 32; ++k)
                acc += W4[l*512 + uu*32 + k] * Ws[l*1024 + k*32 + w];
            acc *= SCALE_M2;
        }
        Ms[l*1536 + u*32 + w] = acc;
    } else if (idx < 3200 + 3*1536 + 3*768) {
        int tix = idx - 3200 - 3*1536;
        int l = tix / 768, rem = tix % 768;
        int u = rem >> 4, w = rem & 15;
        float acc = 0.f;
        if (u < 32) {
            for (int k = 0; k < 16; ++k)
                acc += W2[l*512 + u*16 + k] * Wv[l*256 + k*16 + w];
        } else {
            int uu = u - 32;
            for (int k = 0; k < 16; ++k)
                acc += W3[l*256 + uu*16 + k] * Wv[l*256 + k*16 + w];
        }
        Mv[l*768 + u*16 + w] = acc * SCALE_M34;
    }
}

// ---------------------------------------------------------------------------
// Phase-2 contribution from quad-lane TT (DPP broadcasts + folded-M FMAs).
// ---------------------------------------------------------------------------
template<int TT>
__device__ __forceinline__ void p2(const float (&a0)[8], const float (&a1)[8][3],
                                   const float (&a2)[4][3], const float (&a3)[4],
                                   const float* __restrict__ Msg,
                                   const float* __restrict__ Mvg,
                                   int t, bool hasv,
                                   float (&po)[8], float (&pv)[12])
{
    #pragma unroll
    for (int k = 0; k < 8; ++k) {
        const int u = 8*TT + k;
        float a  = qb<TT>(a0[k]);
        float bx = qb<TT>(a1[k][0]);
        float by = qb<TT>(a1[k][1]);
        float bz = qb<TT>(a1[k][2]);
        const float4* r = (const float4*)(Msg + u*32 + 8*t);
        float4 rA = r[0], rB = r[1];
        po[0]=fmaf(a,rA.x,po[0]); po[1]=fmaf(a,rA.y,po[1]);
        po[2]=fmaf(a,rA.z,po[2]); po[3]=fmaf(a,rA.w,po[3]);
        po[4]=fmaf(a,rB.x,po[4]); po[5]=fmaf(a,rB.y,po[5]);
        po[6]=fmaf(a,rB.z,po[6]); po[7]=fmaf(a,rB.w,po[7]);
        float4 m = *(const float4*)(Mvg + u*16 + 4*t);
        pv[0]=fmaf(m.x,bx,pv[0]);  pv[1]=fmaf(m.x,by,pv[1]);  pv[2]=fmaf(m.x,bz,pv[2]);
        pv[3]=fmaf(m.y,bx,pv[3]);  pv[4]=fmaf(m.y,by,pv[4]);  pv[5]=fmaf(m.y,bz,pv[5]);
        pv[6]=fmaf(m.z,bx,pv[6]);  pv[7]=fmaf(m.z,by,pv[7]);  pv[8]=fmaf(m.z,bz,pv[8]);
        pv[9]=fmaf(m.w,bx,pv[9]);  pv[10]=fmaf(m.w,by,pv[10]); pv[11]=fmaf(m.w,bz,pv[11]);
    }
    if (hasv) {
        #pragma unroll
        for (int k = 0; k < 4; ++k) {
            const int u = 32 + 4*TT + k;
            float a  = qb<TT>(a3[k]);
            float bx = qb<TT>(a2[k][0]);
            float by = qb<TT>(a2[k][1]);
            float bz = qb<TT>(a2[k][2]);
            const float4* r = (const float4*)(Msg + u*32 + 8*t);
            float4 rA = r[0], rB = r[1];
            po[0]=fmaf(a,rA.x,po[0]); po[1]=fmaf(a,rA.y,po[1]);
            po[2]=fmaf(a,rA.z,po[2]); po[3]=fmaf(a,rA.w,po[3]);
            po[4]=fmaf(a,rB.x,po[4]); po[5]=fmaf(a,rB.y,po[5]);
            po[6]=fmaf(a,rB.z,po[6]); po[7]=fmaf(a,rB.w,po[7]);
            float4 m = *(const float4*)(Mvg + u*16 + 4*t);
            pv[0]=fmaf(m.x,bx,pv[0]);  pv[1]=fmaf(m.x,by,pv[1]);  pv[2]=fmaf(m.x,bz,pv[2]);
            pv[3]=fmaf(m.y,bx,pv[3]);  pv[4]=fmaf(m.y,by,pv[4]);  pv[5]=fmaf(m.y,bz,pv[5]);
            pv[6]=fmaf(m.z,bx,pv[6]);  pv[7]=fmaf(m.z,by,pv[7]);  pv[8]=fmaf(m.z,bz,pv[8]);
            pv[9]=fmaf(m.w,bx,pv[9]);  pv[10]=fmaf(m.w,by,pv[10]); pv[11]=fmaf(m.w,bz,pv[11]);
        }
    }
}

// ---------------------------------------------------------------------------
// Fused GNN: one block = 2 graphs (64 nodes, 256 threads, 4 lanes/node).
// s,v AND the block's packed edge table live in LDS across all 3 layers.
// Edge record: 8 B = fp16 shx,shy,shz + 16-bit local j. 64*31=1984 <= ECAP.
// ---------------------------------------------------------------------------
__global__ __launch_bounds__(256, 4)
void gnn_kernel(const float* __restrict__ T, const int* __restrict__ z,
                const int* __restrict__ rowptr, const float4* __restrict__ jsh,
                const float* __restrict__ Ms, const float* __restrict__ Mv,
                float* __restrict__ hg, int N)
{
    __shared__ __align__(16) float sS[64*SSTR];
    __shared__ __align__(16) float sV[64*VSTR];
    __shared__ __align__(16) uint2 sE[ECAP];
    __shared__ int rp[65];

    const int base = blockIdx.x * 64;
    const int tid = threadIdx.x;

    if (tid < 65) rp[tid] = rowptr[base + tid];
    for (int i = tid; i < 64*VSTR; i += 256) sV[i] = 0.f;
    for (int i = tid; i < 2048; i += 256) {
        int n = i >> 5, c = i & 31;
        sS[n*SSTR + c] = T[z[base + n]*32 + c];
    }
    __syncthreads();

    const int eb0 = rp[0];
    const int ecnt = rp[64] - eb0;
    for (int i = tid; i < ecnt; i += 256) {
        float4 js = jsh[eb0 + i];
        unsigned j6 = (unsigned)__float_as_int(js.w);
        unsigned hx = __half_as_ushort(__float2half(js.x));
        unsigned hy = __half_as_ushort(__float2half(js.y));
        unsigned hz = __half_as_ushort(__float2half(js.z));
        sE[i] = make_uint2(hx | (hy << 16), hz | (j6 << 16));
    }
    __syncthreads();

    const int nl = tid >> 2;    // node 0..63 within block
    const int t  = tid & 3;     // quad lane: s-channels 8t.., v-channels 4t..
    const int el0 = rp[nl] - eb0, el1 = rp[nl + 1] - eb0;

    for (int lay = 0; lay < 3; ++lay) {
        const bool hasv = (lay != 0);
        const float* Msg = Ms + lay*1536;
        const float* Mvg = Mv + lay*768;

        float a0[8]    = {};
        float a1[8][3] = {};
        float a2[4][3] = {};
        float a3[4]    = {};

        uint2 ep = (el0 < el1) ? sE[el0] : make_uint2(0u, 0u);
        if (!hasv) {
            for (int e = el0; e < el1; ++e) {
                uint2 cur = ep;
                if (e + 1 < el1) ep = sE[e + 1];
                int jl = (int)(cur.y >> 16);
                float shx = __half2float(__ushort_as_half((unsigned short)(cur.x & 0xFFFFu)));
                float shy = __half2float(__ushort_as_half((unsigned short)(cur.x >> 16)));
                float shz = __half2float(__ushort_as_half((unsigned short)(cur.y & 0xFFFFu)));
                const float* Sj = sS + jl*SSTR + 8*t;
                float4 sA = *(const float4*)Sj;
                float4 sB = *(const float4*)(Sj + 4);
                float ssv[8] = {sA.x,sA.y,sA.z,sA.w,sB.x,sB.y,sB.z,sB.w};
                #pragma unroll
                for (int k = 0; k < 8; ++k) {
                    a0[k] += ssv[k];
                    a1[k][0] = fmaf(ssv[k], shx, a1[k][0]);
                    a1[k][1] = fmaf(ssv[k], shy, a1[k][1]);
                    a1[k][2] = fmaf(ssv[k], shz, a1[k][2]);
                }
            }
        } else {
            for (int e = el0; e < el1; ++e) {
                uint2 cur = ep;
                if (e + 1 < el1) ep = sE[e + 1];
                int jl = (int)(cur.y >> 16);
                float shx = __half2float(__ushort_as_half((unsigned short)(cur.x & 0xFFFFu)));
                float shy = __half2float(__ushort_as_half((unsigned short)(cur.x >> 16)));
                float shz = __half2float(__ushort_as_half((unsigned short)(cur.y & 0xFFFFu)));
                const float* Sj = sS + jl*SSTR + 8*t;
                const float* Vj = sV + jl*VSTR + 12*t;
                float4 sA = *(const float4*)Sj;
                float4 sB = *(const float4*)(Sj + 4);
                float4 vA = *(const float4*)Vj;
                float4 vB = *(const float4*)(Vj + 4);
                float4 vC = *(const float4*)(Vj + 8);
                float ssv[8] = {sA.x,sA.y,sA.z,sA.w,sB.x,sB.y,sB.z,sB.w};
                #pragma unroll
                for (int k = 0; k < 8; ++k) {
                    a0[k] += ssv[k];
                    a1[k][0] = fmaf(ssv[k], shx, a1[k][0]);
                    a1[k][1] = fmaf(ssv[k], shy, a1[k][1]);
                    a1[k][2] = fmaf(ssv[k], shz, a1[k][2]);
                }
                float vv[4][3] = {{vA.x,vA.y,vA.z},{vA.w,vB.x,vB.y},
                                  {vB.z,vB.w,vC.x},{vC.y,vC.z,vC.w}};
                #pragma unroll
                for (int k = 0; k < 4; ++k) {
                    a2[k][0] += vv[k][0]; a2[k][1] += vv[k][1]; a2[k][2] += vv[k][2];
                    a3[k] = fmaf(vv[k][0], shx,
                            fmaf(vv[k][1], shy, fmaf(vv[k][2], shz, a3[k])));
                }
            }
        }
        __syncthreads();   // all gathers done before in-place update

        float po[8]  = {};
        float pv[12] = {};
        p2<0>(a0, a1, a2, a3, Msg, Mvg, t, hasv, po, pv);
        p2<1>(a0, a1, a2, a3, Msg, Mvg, t, hasv, po, pv);
        p2<2>(a0, a1, a2, a3, Msg, Mvg, t, hasv, po, pv);
        p2<3>(a0, a1, a2, a3, Msg, Mvg, t, hasv, po, pv);

        // residual + relu, in-place (lane-owned slices only)
        float* Sp = sS + nl*SSTR + 8*t;
        float4 s0 = *(float4*)Sp, s1 = *(float4*)(Sp + 4);
        s0.x += fmaxf(po[0],0.f); s0.y += fmaxf(po[1],0.f);
        s0.z += fmaxf(po[2],0.f); s0.w += fmaxf(po[3],0.f);
        s1.x += fmaxf(po[4],0.f); s1.y += fmaxf(po[5],0.f);
        s1.z += fmaxf(po[6],0.f); s1.w += fmaxf(po[7],0.f);
        *(float4*)Sp = s0; *(float4*)(Sp + 4) = s1;

        float* Vp = sV + nl*VSTR + 12*t;
        float4 v0 = *(float4*)Vp, v1 = *(float4*)(Vp + 4), v2 = *(float4*)(Vp + 8);
        v0.x += fmaxf(pv[0],0.f);  v0.y += fmaxf(pv[1],0.f);
        v0.z += fmaxf(pv[2],0.f);  v0.w += fmaxf(pv[3],0.f);
        v1.x += fmaxf(pv[4],0.f);  v1.y += fmaxf(pv[5],0.f);
        v1.z += fmaxf(pv[6],0.f);  v1.w += fmaxf(pv[7],0.f);
        v2.x += fmaxf(pv[8],0.f);  v2.y += fmaxf(pv[9],0.f);
        v2.z += fmaxf(pv[10],0.f); v2.w += fmaxf(pv[11],0.f);
        *(float4*)Vp = v0; *(float4*)(Vp + 4) = v1; *(float4*)(Vp + 8) = v2;

        __syncthreads();
    }

    // fused sum-pool: 2 graphs x 80 features
    if (tid < 160) {
        int g = tid / 80, f = tid - g*80;
        float acc = 0.f;
        if (f < 32) {
            for (int k = 0; k < 32; ++k) acc += sS[(g*32 + k)*SSTR + f];
        } else {
            int c = f - 32;
            for (int k = 0; k < 32; ++k) acc += sV[(g*32 + k)*VSTR + c];
        }
        hg[(size_t)(blockIdx.x*2 + g)*80 + f] = acc;
    }
}

// ---------------------------------------------------------------------------
// MLP head: 4 graphs per block; Wr1/Wr2 shared; split-K stage 2.
// ---------------------------------------------------------------------------
__launch_bounds__(256)
__global__ void mlp_kernel(const float* __restrict__ hg,
                           const float* __restrict__ Wr1, const float* __restrict__ br1,
                           const float* __restrict__ Wr2, const float* __restrict__ br2,
                           float* __restrict__ out, int B)
{
    __shared__ __align__(16) float h1[4][256];
    __shared__ float red[4][128];
    const int g0 = blockIdx.x * 4;
    const int w = threadIdx.x;

    float acc0 = br1[w];
    float acc1 = acc0, acc2 = acc0, acc3 = acc0;
    #pragma unroll 4
    for (int f = 0; f < 80; ++f) {
        float wv = Wr1[f*256 + w];
        acc0 = fmaf(hg[(size_t)(g0+0)*80 + f], wv, acc0);
        acc1 = fmaf(hg[(size_t)(g0+1)*80 + f], wv, acc1);
        acc2 = fmaf(hg[(size_t)(g0+2)*80 + f], wv, acc2);
        acc3 = fmaf(hg[(size_t)(g0+3)*80 + f], wv, acc3);
    }
    h1[0][w] = fmaxf(acc0, 0.f);
    h1[1][w] = fmaxf(acc1, 0.f);
    h1[2][w] = fmaxf(acc2, 0.f);
    h1[3][w] = fmaxf(acc3, 0.f);
    __syncthreads();

    const int w2 = threadIdx.x & 127, kh = threadIdx.x >> 7;
    const float4* h1v = (const float4*)(&h1[0][0]);   // [4][64] float4 view
    float s0 = 0.f, s1 = 0.f, s2 = 0.f, s3 = 0.f;
    #pragma unroll 2
    for (int k4 = kh*32; k4 < kh*32 + 32; ++k4) {
        float4 hA = h1v[0*64 + k4];
        float4 hB = h1v[1*64 + k4];
        float4 hC = h1v[2*64 + k4];
        float4 hD = h1v[3*64 + k4];
        int k = k4 * 4;
        float m0 = Wr2[(size_t)(k+0)*128 + w2];
        float m1 = Wr2[(size_t)(k+1)*128 + w2];
        float m2 = Wr2[(size_t)(k+2)*128 + w2];
        float m3 = Wr2[(size_t)(k+3)*128 + w2];
        s0 = fmaf(hA.x,m0, fmaf(hA.y,m1, fmaf(hA.z,m2, fmaf(hA.w,m3, s0))));
        s1 = fmaf(hB.x,m0, fmaf(hB.y,m1, fmaf(hB.z,m2, fmaf(hB.w,m3, s1))));
        s2 = fmaf(hC.x,m0, fmaf(hC.y,m1, fmaf(hC.z,m2, fmaf(hC.w,m3, s2))));
        s3 = fmaf(hD.x,m0, fmaf(hD.y,m1, fmaf(hD.z,m2, fmaf(hD.w,m3, s3))));
    }
    if (kh) {
        red[0][w2] = s0; red[1][w2] = s1; red[2][w2] = s2; red[3][w2] = s3;
    }
    __syncthreads();
    if (!kh) {
        float b = br2[w2];
        out[(size_t)(g0+0)*128 + w2] = s0 + red[0][w2] + b;
        out[(size_t)(g0+1)*128 + w2] = s1 + red[1][w2] + b;
        out[(size_t)(g0+2)*128 + w2] = s2 + red[2][w2] + b;
        out[(size_t)(g0+3)*128 + w2] = s3 + red[3][w2] + b;
    }
}

// ---------------------------------------------------------------------------
extern "C" void kernel_launch(void* const* d_in, const int* in_sizes, int n_in,
                              void* d_out, int out_size, void* d_ws, size_t ws_size,
                              hipStream_t stream)
{
    const float* pos   = (const float*)d_in[0];
    const int*   z     = (const int*)d_in[1];
    const int*   eidx  = (const int*)d_in[3];
    const float* emb   = (const float*)d_in[5];
    const float* W_s2n = (const float*)d_in[6];
    const float* W1    = (const float*)d_in[7];
    const float* W2    = (const float*)d_in[8];
    const float* W3    = (const float*)d_in[9];
    const float* W4    = (const float*)d_in[10];
    const float* Ws    = (const float*)d_in[11];
    const float* Wv    = (const float*)d_in[12];
    const float* Wr1   = (const float*)d_in[13];
    const float* br1   = (const float*)d_in[14];
    const float* Wr2   = (const float*)d_in[15];
    const float* br2   = (const float*)d_in[16];
    float* out = (float*)d_out;

    const int N = in_sizes[0] / 3;
    const int E = in_sizes[3] / 2;
    const int B = out_size / 128;

    const int* src = eidx;
    const int* col = eidx + E;

    // workspace layout (16B-aligned chunks)
    char* p = (char*)d_ws;
    float4* jsh = (float4*)p;  p += (size_t)E * 16;
    float* T  = (float*)p;     p += 3200 * 4;
    float* Ms = (float*)p;     p += 3 * 1536 * 4;
    float* Mv = (float*)p;     p += 3 * 768 * 4;
    int* rowptr = (int*)p;     p += (((size_t)(N + 1) * 4 + 15) & ~(size_t)15);
    float* hg = (float*)p;     p += (size_t)B * 80 * 4;

    const int prep_total = E + (N + 1) + 3200 + 3*1536 + 3*768;
    prep_kernel<<<(prep_total + 255) / 256, 256, 0, stream>>>(
        pos, src, col, E, N, emb, W_s2n, W1, W2, W3, W4, Ws, Wv,
        jsh, rowptr, T, Ms, Mv);

    gnn_kernel<<<(N + 63) / 64, 256, 0, stream>>>(T, z, rowptr, jsh, Ms, Mv, hg, N);

    mlp_kernel<<<B / 4, 256, 0, stream>>>(hg, Wr1, br1, Wr2, br2, out, B);
}